// Round 3
// baseline (680.373 us; speedup 1.0000x reference)
//
#include <hip/hip_runtime.h>
#include <hip/hip_bf16.h>

#define NB 16
#define NL 2048
#define ND 128
#define QSCALE 0.08838834764831845f

using short8 = __attribute__((ext_vector_type(8))) short;
using f32x4  = __attribute__((ext_vector_type(4))) float;

// fp32 -> bf16 bits, round-to-nearest-even
__device__ __forceinline__ unsigned short bfr(float f) {
  unsigned u = __float_as_uint(f);
  unsigned r = u + 0x7FFFu + ((u >> 16) & 1u);
  return (unsigned short)(r >> 16);
}
__device__ __forceinline__ float bf2f(unsigned short h) {
  return __uint_as_float(((unsigned)h) << 16);
}

// Workspace layout (bytes):
//   Kb  bf16 [B][L][D]  @ 0          (16*2048*128*2 = 8388608)
//   Vt  bf16 [B][D][L]  @ 8388608    (8388608)
//   linv f32 [B][L]     @ 16777216   (131072)
#define WS_KB 0
#define WS_VT 8388608
#define WS_LINV 16777216
#define WS_NEED 16908288

// ---------------- kernel 0: convert K -> bf16; transpose+convert V -> bf16 ----------------
// grid (4096, 1, 2), block 256. z=0: K convert (4 elems/thread). z=1: V transpose.
__global__ __launch_bounds__(256)
void prep_kv(const float* __restrict__ kg, const float* __restrict__ vg,
             unsigned short* __restrict__ Kb, unsigned short* __restrict__ Vt) {
  const int tid = threadIdx.x;
  if (blockIdx.z == 0) {
    size_t base = ((size_t)blockIdx.x * 256 + tid) * 4;
    float4 x = *(const float4*)(kg + base);
    ushort4 o;
    o.x = bfr(x.x); o.y = bfr(x.y); o.z = bfr(x.z); o.w = bfr(x.w);
    *(ushort4*)(Kb + base) = o;
  } else {
    int linear = blockIdx.x * 256 + tid;      // 0 .. 1048575
    int b  = linear >> 16;                    // 65536 per batch
    int rem = linear & 65535;
    int d  = rem & 127;
    int jg = rem >> 7;                        // 0..511 (4 j's each)
    const float* vb = vg + (size_t)b * NL * ND;
    ushort4 o;
    o.x = bfr(vb[((size_t)jg * 4 + 0) * ND + d]);
    o.y = bfr(vb[((size_t)jg * 4 + 1) * ND + d]);
    o.z = bfr(vb[((size_t)jg * 4 + 2) * ND + d]);
    o.w = bfr(vb[((size_t)jg * 4 + 3) * ND + d]);
    *(ushort4*)(Vt + ((size_t)b * ND + d) * NL + jg * 4) = o;
  }
}

// Build split-precision Q fragments for 16 rows (A-layout m=l16, k=quad*8+t)
__device__ __forceinline__ void load_q_frags(const float* qrow, int quad,
                                             short8* qh, short8* ql) {
#pragma unroll
  for (int kk = 0; kk < 4; ++kk) {
    const float* p = qrow + kk * 32 + quad * 8;
    float4 x = *(const float4*)(p);
    float4 y = *(const float4*)(p + 4);
    float e[8] = {x.x, x.y, x.z, x.w, y.x, y.y, y.z, y.w};
    short8 th, tl;
#pragma unroll
    for (int t = 0; t < 8; ++t) {
      float qs = e[t] * QSCALE;
      unsigned short h = bfr(qs);
      th[t] = (short)h;
      tl[t] = (short)bfr(qs - bf2f(h));
    }
    qh[kk] = th;
    ql[kk] = tl;
  }
}

// ---------------- kernel A: ctx + linv (flash pass 1) ----------------
// grid (64, 16), block 256 = 4 waves. wave: rg = w&1 (16-row group), jh = w>>1 (j-half).
// Barrier-free main loop; K/V fragments load DIRECTLY from global bf16 (no staging LDS).
__global__ __launch_bounds__(256, 4)
void attn_ctx(const float* __restrict__ q, const unsigned short* __restrict__ Kb,
              const unsigned short* __restrict__ Vt,
              float* __restrict__ ctx, float* __restrict__ linv_ws) {
  const int b    = blockIdx.y;
  const int i0   = blockIdx.x * 32;
  const int tid  = threadIdx.x;
  const int wave = tid >> 6;
  const int lane = tid & 63;
  const int quad = lane >> 4;
  const int l16  = lane & 15;
  const int rg   = wave & 1;
  const int jh   = wave >> 1;

  __shared__ unsigned short Ps[4][16][40]; // per-wave P tile (i x j), pad->~2-way max
  __shared__ float Ob[2][16][132];         // jh=1 partial O (pitch 132 breaks conflicts)
  __shared__ float lbuf[2][16];            // jh=1 partial row sums

  const float* qrow = q + ((size_t)b * NL + i0 + rg * 16 + l16) * ND;
  short8 qh[4], ql[4];
  load_q_frags(qrow, quad, qh, ql);

  f32x4 oacc[8];
#pragma unroll
  for (int i = 0; i < 8; ++i) oacc[i] = (f32x4){0.f, 0.f, 0.f, 0.f};
  float lsum[4] = {0.f, 0.f, 0.f, 0.f};

  const unsigned short* kbb = Kb + (size_t)b * NL * ND;
  const unsigned short* vtb = Vt + (size_t)b * ND * NL;

  const int jbase = jh * (NL / 2);
  for (int jt = 0; jt < NL / 2; jt += 32) {
    const int j0 = jbase + jt;
    // ---- S = (q_hi + q_lo) K^T : 16 rows x 32 cols ----
    f32x4 a0 = {0.f, 0.f, 0.f, 0.f}, a1 = {0.f, 0.f, 0.f, 0.f};
#pragma unroll
    for (int kk = 0; kk < 4; ++kk) {
      short8 k0 = *(const short8*)&kbb[(size_t)(j0 + l16) * ND + kk * 32 + quad * 8];
      short8 k1 = *(const short8*)&kbb[(size_t)(j0 + 16 + l16) * ND + kk * 32 + quad * 8];
      a0 = __builtin_amdgcn_mfma_f32_16x16x32_bf16(qh[kk], k0, a0, 0, 0, 0);
      a0 = __builtin_amdgcn_mfma_f32_16x16x32_bf16(ql[kk], k0, a0, 0, 0, 0);
      a1 = __builtin_amdgcn_mfma_f32_16x16x32_bf16(qh[kk], k1, a1, 0, 0, 0);
      a1 = __builtin_amdgcn_mfma_f32_16x16x32_bf16(ql[kk], k1, a1, 0, 0, 0);
    }
    // ---- e = exp(S), row-sum partials, P -> wave-private LDS (C-layout -> row-major) ----
#pragma unroll
    for (int r = 0; r < 4; ++r) {
      float e0 = __expf(a0[r]);
      float e1 = __expf(a1[r]);
      lsum[r] += e0 + e1;
      Ps[wave][quad * 4 + r][l16]      = bfr(e0);
      Ps[wave][quad * 4 + r][l16 + 16] = bfr(e1);
    }
    // wave-private LDS: compiler orders via lgkmcnt, no barrier
    short8 pa = *(const short8*)&Ps[wave][l16][quad * 8];
    // ---- O += P * V (B-frag = V^T direct from global) ----
#pragma unroll
    for (int dt = 0; dt < 8; ++dt) {
      short8 vf = *(const short8*)&vtb[(size_t)(dt * 16 + l16) * NL + j0 + quad * 8];
      oacc[dt] = __builtin_amdgcn_mfma_f32_16x16x32_bf16(pa, vf, oacc[dt], 0, 0, 0);
    }
  }

  // ---- reduce row sums across the 16 lanes of each quad ----
  float lred[4];
#pragma unroll
  for (int r = 0; r < 4; ++r) {
    float s = lsum[r];
    s += __shfl_xor(s, 1, 16);
    s += __shfl_xor(s, 2, 16);
    s += __shfl_xor(s, 4, 16);
    s += __shfl_xor(s, 8, 16);
    lred[r] = s;
  }

  if (jh == 1) {
#pragma unroll
    for (int r = 0; r < 4; ++r) {
#pragma unroll
      for (int dt = 0; dt < 8; ++dt)
        Ob[rg][quad * 4 + r][dt * 16 + l16] = oacc[dt][r];
      if (l16 == 0) lbuf[rg][quad * 4 + r] = lred[r];
    }
  }
  __syncthreads();
  if (jh == 0) {
#pragma unroll
    for (int r = 0; r < 4; ++r) {
      float tot = lred[r] + lbuf[rg][quad * 4 + r];
      float li = 1.0f / tot;
      if (l16 == 0) linv_ws[(size_t)b * NL + i0 + rg * 16 + quad * 4 + r] = li;
      float* crow = ctx + ((size_t)b * NL + i0 + rg * 16 + quad * 4 + r) * ND;
#pragma unroll
      for (int dt = 0; dt < 8; ++dt)
        crow[dt * 16 + l16] = (oacc[dt][r] + Ob[rg][quad * 4 + r][dt * 16 + l16]) * li;
    }
  }
}

// ---------------- kernel B: attention = exp(S) * linv, fully parallel ----------------
// grid (L/128, L/64, B) = (16, 32, 16), block 256 = 4 waves x 16 q-rows. No LDS.
__global__ __launch_bounds__(256, 4)
void attn_probs(const float* __restrict__ q, const unsigned short* __restrict__ Kb,
                const float* __restrict__ linv_ws, float* __restrict__ attn) {
  const int b    = blockIdx.z;
  const int i0   = blockIdx.y * 64;
  const int j0   = blockIdx.x * 128;
  const int tid  = threadIdx.x;
  const int wave = tid >> 6;
  const int lane = tid & 63;
  const int quad = lane >> 4;
  const int l16  = lane & 15;

  const int row0 = i0 + wave * 16;
  const float* qrow = q + ((size_t)b * NL + row0 + l16) * ND;
  short8 qh[4], ql[4];
  load_q_frags(qrow, quad, qh, ql);

  float li[4];
#pragma unroll
  for (int r = 0; r < 4; ++r)
    li[r] = linv_ws[(size_t)b * NL + row0 + quad * 4 + r];

  const unsigned short* kbb = Kb + (size_t)b * NL * ND;

#pragma unroll
  for (int jt = 0; jt < 128; jt += 32) {
    const int j = j0 + jt;
    f32x4 a0 = {0.f, 0.f, 0.f, 0.f}, a1 = {0.f, 0.f, 0.f, 0.f};
#pragma unroll
    for (int kk = 0; kk < 4; ++kk) {
      short8 k0 = *(const short8*)&kbb[(size_t)(j + l16) * ND + kk * 32 + quad * 8];
      short8 k1 = *(const short8*)&kbb[(size_t)(j + 16 + l16) * ND + kk * 32 + quad * 8];
      a0 = __builtin_amdgcn_mfma_f32_16x16x32_bf16(qh[kk], k0, a0, 0, 0, 0);
      a0 = __builtin_amdgcn_mfma_f32_16x16x32_bf16(ql[kk], k0, a0, 0, 0, 0);
      a1 = __builtin_amdgcn_mfma_f32_16x16x32_bf16(qh[kk], k1, a1, 0, 0, 0);
      a1 = __builtin_amdgcn_mfma_f32_16x16x32_bf16(ql[kk], k1, a1, 0, 0, 0);
    }
    float* arow = attn + ((size_t)b * NL + row0 + quad * 4) * NL + j;
#pragma unroll
    for (int r = 0; r < 4; ++r) {
      arow[(size_t)r * NL + l16]      = __expf(a0[r]) * li[r];
      arow[(size_t)r * NL + l16 + 16] = __expf(a1[r]) * li[r];
    }
  }
}

// ---------------- fallback: round-2 monolithic kernel (used if ws too small) ----------------
__global__ __launch_bounds__(256, 2)
void attn_fused(const float* __restrict__ q, const float* __restrict__ kg,
                const float* __restrict__ vg, float* __restrict__ out) {
  float* ctx  = out;
  float* attn = out + (size_t)NB * NL * ND;
  const int b    = blockIdx.y;
  const int i0   = blockIdx.x * 64;
  const int tid  = threadIdx.x;
  const int wave = tid >> 6;
  const int lane = tid & 63;
  const int quad = lane >> 4;
  const int l16  = lane & 15;

  __shared__ short Ks[32][136];
  __shared__ short Vt[128][40];
  __shared__ short Ps2[4][16][40];

  const float* qrow = q + ((size_t)b * NL + i0 + wave * 16 + l16) * ND;
  short8 qh[4], ql[4];
  load_q_frags(qrow, quad, qh, ql);

  f32x4 oacc[8];
#pragma unroll
  for (int i = 0; i < 8; ++i) oacc[i] = (f32x4){0.f, 0.f, 0.f, 0.f};
  float lsum[4] = {0.f, 0.f, 0.f, 0.f};

  const float* kb = kg + (size_t)b * NL * ND;
  const float* vb = vg + (size_t)b * NL * ND;

  for (int j0 = 0; j0 < NL; j0 += 32) {
    __syncthreads();
#pragma unroll
    for (int rr = 0; rr < 4; ++rr) {
      int idx = tid + rr * 256;
      int row = idx >> 5;
      int c4  = idx & 31;
      float4 kv = *(const float4*)(kb + (size_t)(j0 + row) * ND + c4 * 4);
      ushort4 ks;
      ks.x = bfr(kv.x); ks.y = bfr(kv.y); ks.z = bfr(kv.z); ks.w = bfr(kv.w);
      *(ushort4*)&Ks[row][c4 * 4] = ks;
      float4 vv = *(const float4*)(vb + (size_t)(j0 + row) * ND + c4 * 4);
      Vt[c4 * 4 + 0][row] = (short)bfr(vv.x);
      Vt[c4 * 4 + 1][row] = (short)bfr(vv.y);
      Vt[c4 * 4 + 2][row] = (short)bfr(vv.z);
      Vt[c4 * 4 + 3][row] = (short)bfr(vv.w);
    }
    __syncthreads();

    f32x4 a0 = {0.f, 0.f, 0.f, 0.f}, a1 = {0.f, 0.f, 0.f, 0.f};
#pragma unroll
    for (int kk = 0; kk < 4; ++kk) {
      short8 k0 = *(const short8*)&Ks[l16][kk * 32 + quad * 8];
      short8 k1 = *(const short8*)&Ks[l16 + 16][kk * 32 + quad * 8];
      a0 = __builtin_amdgcn_mfma_f32_16x16x32_bf16(qh[kk], k0, a0, 0, 0, 0);
      a0 = __builtin_amdgcn_mfma_f32_16x16x32_bf16(ql[kk], k0, a0, 0, 0, 0);
      a1 = __builtin_amdgcn_mfma_f32_16x16x32_bf16(qh[kk], k1, a1, 0, 0, 0);
      a1 = __builtin_amdgcn_mfma_f32_16x16x32_bf16(ql[kk], k1, a1, 0, 0, 0);
    }
#pragma unroll
    for (int r = 0; r < 4; ++r) {
      float e0 = __expf(a0[r]);
      float e1 = __expf(a1[r]);
      lsum[r] += e0 + e1;
      Ps2[wave][quad * 4 + r][l16]      = (short)bfr(e0);
      Ps2[wave][quad * 4 + r][l16 + 16] = (short)bfr(e1);
    }
    __syncthreads();
    short8 pa = *(const short8*)&Ps2[wave][l16][quad * 8];
#pragma unroll
    for (int dt = 0; dt < 8; ++dt) {
      short8 vf = *(const short8*)&Vt[dt * 16 + l16][quad * 8];
      oacc[dt] = __builtin_amdgcn_mfma_f32_16x16x32_bf16(pa, vf, oacc[dt], 0, 0, 0);
    }
  }

  float linv[4];
#pragma unroll
  for (int r = 0; r < 4; ++r) {
    float s = lsum[r];
    s += __shfl_xor(s, 1, 16);
    s += __shfl_xor(s, 2, 16);
    s += __shfl_xor(s, 4, 16);
    s += __shfl_xor(s, 8, 16);
    linv[r] = 1.0f / s;
  }
#pragma unroll
  for (int r = 0; r < 4; ++r) {
    float* crow = ctx + ((size_t)b * NL + i0 + wave * 16 + quad * 4 + r) * ND;
#pragma unroll
    for (int dt = 0; dt < 8; ++dt)
      crow[dt * 16 + l16] = oacc[dt][r] * linv[r];
  }

  for (int j0 = 0; j0 < NL; j0 += 32) {
    __syncthreads();
#pragma unroll
    for (int rr = 0; rr < 4; ++rr) {
      int idx = tid + rr * 256;
      int row = idx >> 5;
      int c4  = idx & 31;
      float4 kv = *(const float4*)(kb + (size_t)(j0 + row) * ND + c4 * 4);
      ushort4 ks;
      ks.x = bfr(kv.x); ks.y = bfr(kv.y); ks.z = bfr(kv.z); ks.w = bfr(kv.w);
      *(ushort4*)&Ks[row][c4 * 4] = ks;
    }
    __syncthreads();
    f32x4 a0 = {0.f, 0.f, 0.f, 0.f}, a1 = {0.f, 0.f, 0.f, 0.f};
#pragma unroll
    for (int kk = 0; kk < 4; ++kk) {
      short8 k0 = *(const short8*)&Ks[l16][kk * 32 + quad * 8];
      short8 k1 = *(const short8*)&Ks[l16 + 16][kk * 32 + quad * 8];
      a0 = __builtin_amdgcn_mfma_f32_16x16x32_bf16(qh[kk], k0, a0, 0, 0, 0);
      a0 = __builtin_amdgcn_mfma_f32_16x16x32_bf16(ql[kk], k0, a0, 0, 0, 0);
      a1 = __builtin_amdgcn_mfma_f32_16x16x32_bf16(qh[kk], k1, a1, 0, 0, 0);
      a1 = __builtin_amdgcn_mfma_f32_16x16x32_bf16(ql[kk], k1, a1, 0, 0, 0);
    }
    float* arow = attn + ((size_t)b * NL + i0 + wave * 16 + quad * 4) * NL + j0;
#pragma unroll
    for (int r = 0; r < 4; ++r) {
      arow[(size_t)r * NL + l16]      = __expf(a0[r]) * linv[r];
      arow[(size_t)r * NL + l16 + 16] = __expf(a1[r]) * linv[r];
    }
  }
}

extern "C" void kernel_launch(void* const* d_in, const int* in_sizes, int n_in,
                              void* d_out, int out_size, void* d_ws, size_t ws_size,
                              hipStream_t stream) {
  const float* q = (const float*)d_in[0];
  const float* k = (const float*)d_in[1];
  const float* v = (const float*)d_in[2];
  float* out = (float*)d_out;

  if (ws_size >= (size_t)WS_NEED) {
    unsigned short* Kb = (unsigned short*)((char*)d_ws + WS_KB);
    unsigned short* Vt = (unsigned short*)((char*)d_ws + WS_VT);
    float* linv        = (float*)((char*)d_ws + WS_LINV);
    float* ctx  = out;
    float* attn = out + (size_t)NB * NL * ND;

    prep_kv<<<dim3(4096, 1, 2), dim3(256), 0, stream>>>(k, v, Kb, Vt);
    attn_ctx<<<dim3(64, 16), dim3(256), 0, stream>>>(q, Kb, Vt, ctx, linv);
    attn_probs<<<dim3(16, 32, 16), dim3(256), 0, stream>>>(q, Kb, linv, attn);
  } else {
    dim3 grid(NL / 64, NB);
    attn_fused<<<grid, dim3(256), 0, stream>>>(q, k, v, out);
  }
}

// Round 4
// 482.664 us; speedup vs baseline: 1.4096x; 1.4096x over previous
//
#include <hip/hip_runtime.h>
#include <hip/hip_bf16.h>

#define NB 16
#define NL 2048
#define ND 128
#define QSCALE 0.08838834764831845f

using short8 = __attribute__((ext_vector_type(8))) short;
using f32x4  = __attribute__((ext_vector_type(4))) float;

// fp32 -> bf16 bits, round-to-nearest-even
__device__ __forceinline__ unsigned short bfr(float f) {
  unsigned u = __float_as_uint(f);
  unsigned r = u + 0x7FFFu + ((u >> 16) & 1u);
  return (unsigned short)(r >> 16);
}
__device__ __forceinline__ float bf2f(unsigned short h) {
  return __uint_as_float(((unsigned)h) << 16);
}

// Workspace layout (bytes):
//   Kb  bf16 [B][L][D]  @ 0          (8388608)
//   Vt  bf16 [B][D][L]  @ 8388608    (8388608)
//   linv f32 [B][L]     @ 16777216   (131072)
#define WS_KB 0
#define WS_VT 8388608
#define WS_LINV 16777216
#define WS_NEED 16908288

// ---------------- prep: K f32 -> bf16, coalesced ----------------
__global__ __launch_bounds__(256)
void prep_k(const float* __restrict__ kg, unsigned short* __restrict__ Kb) {
  size_t base = ((size_t)blockIdx.x * 256 + threadIdx.x) * 4;
  float4 x = *(const float4*)(kg + base);
  ushort4 o;
  o.x = bfr(x.x); o.y = bfr(x.y); o.z = bfr(x.z); o.w = bfr(x.w);
  *(ushort4*)(Kb + base) = o;
}

// ---------------- prep: V f32 -> bf16 transposed [B][D][L], LDS-tiled ----------------
// grid (64 j-tiles, 16 b), block 256. Tile 32 j x 128 d.
__global__ __launch_bounds__(256)
void prep_vt(const float* __restrict__ vg, unsigned short* __restrict__ Vt) {
  __shared__ float T[32][129];
  const int b = blockIdx.y, j0 = blockIdx.x * 32, tid = threadIdx.x;
  const float* vb = vg + ((size_t)b * NL + j0) * ND;
#pragma unroll
  for (int r = 0; r < 4; ++r) {
    int f4 = tid + r * 256;       // 0..1023
    int j  = f4 >> 5;             // 0..31
    int c4 = f4 & 31;             // 0..31
    float4 x = *(const float4*)(vb + (size_t)j * ND + c4 * 4);
    T[j][c4 * 4 + 0] = x.x; T[j][c4 * 4 + 1] = x.y;
    T[j][c4 * 4 + 2] = x.z; T[j][c4 * 4 + 3] = x.w;
  }
  __syncthreads();
  const int d = tid >> 1, h = tid & 1;   // d 0..127, h halves of 32 j
  unsigned short* orow = Vt + ((size_t)b * ND + d) * NL + j0 + h * 16;
#pragma unroll
  for (int g = 0; g < 4; ++g) {
    ushort4 o;
    o.x = bfr(T[h * 16 + g * 4 + 0][d]);
    o.y = bfr(T[h * 16 + g * 4 + 1][d]);
    o.z = bfr(T[h * 16 + g * 4 + 2][d]);
    o.w = bfr(T[h * 16 + g * 4 + 3][d]);
    *(ushort4*)(orow + g * 4) = o;
  }
}

// Build split-precision Q fragments for 16 rows (A-layout m=l16, k=quad*8+t)
__device__ __forceinline__ void load_q_frags(const float* qrow, int quad,
                                             short8* qh, short8* ql) {
#pragma unroll
  for (int kk = 0; kk < 4; ++kk) {
    const float* p = qrow + kk * 32 + quad * 8;
    float4 x = *(const float4*)(p);
    float4 y = *(const float4*)(p + 4);
    float e[8] = {x.x, x.y, x.z, x.w, y.x, y.y, y.z, y.w};
    short8 th, tl;
#pragma unroll
    for (int t = 0; t < 8; ++t) {
      float qs = e[t] * QSCALE;
      unsigned short h = bfr(qs);
      th[t] = (short)h;
      tl[t] = (short)bfr(qs - bf2f(h));
    }
    qh[kk] = th;
    ql[kk] = tl;
  }
}

// ---------------- kernel A: ctx + linv ----------------
// grid (32 i-tiles, 16 b), block 256 = 4 waves x 16 q-rows (64 rows/block).
// j-loop: stage K(128x128) + V^T(128x128) bf16 tiles to padded LDS (coalesced),
// then per 32-col chunk: QK MFMA -> exp -> wave-private P LDS -> PV MFMA.
__global__ __launch_bounds__(256, 2)
void attn_ctx(const float* __restrict__ q, const unsigned short* __restrict__ Kb,
              const unsigned short* __restrict__ Vt,
              float* __restrict__ ctx, float* __restrict__ linv_ws) {
  __shared__ unsigned short Ks[128][132];   // pitch 132: bank-balanced b128 reads
  __shared__ unsigned short Vs[128][132];
  __shared__ unsigned short Ps[4][16][36];  // per-wave P chunk (16 x 32, pad 4)

  const int b    = blockIdx.y;
  const int i0   = blockIdx.x * 64;
  const int tid  = threadIdx.x;
  const int wave = tid >> 6;
  const int lane = tid & 63;
  const int quad = lane >> 4;
  const int l16  = lane & 15;

  const float* qrow = q + ((size_t)b * NL + i0 + wave * 16 + l16) * ND;
  short8 qh[4], ql[4];
  load_q_frags(qrow, quad, qh, ql);

  f32x4 oacc[8];
#pragma unroll
  for (int i = 0; i < 8; ++i) oacc[i] = (f32x4){0.f, 0.f, 0.f, 0.f};
  float lsum[4] = {0.f, 0.f, 0.f, 0.f};

  const unsigned short* kbb = Kb + (size_t)b * NL * ND;
  const unsigned short* vtb = Vt + (size_t)b * ND * NL;

  for (int j0 = 0; j0 < NL; j0 += 128) {
    __syncthreads();
    // ---- stage K tile: rows j0..j0+127, 128 d (16 chunks of 16B per row) ----
#pragma unroll
    for (int r = 0; r < 8; ++r) {
      int c = tid + r * 256;        // chunk 0..2047
      int row = c >> 4, c8 = c & 15;
      *(short8*)&Ks[row][c8 * 8] =
          *(const short8*)(kbb + (size_t)(j0 + row) * ND + c8 * 8);
    }
    // ---- stage V^T tile: rows d 0..127, cols j0..j0+127 ----
#pragma unroll
    for (int r = 0; r < 8; ++r) {
      int c = tid + r * 256;
      int d = c >> 4, c8 = c & 15;
      *(short8*)&Vs[d][c8 * 8] =
          *(const short8*)(vtb + (size_t)d * NL + j0 + c8 * 8);
    }
    __syncthreads();

    // ---- 4 chunks of 32 j-cols each ----
#pragma unroll
    for (int ks = 0; ks < 4; ++ks) {
      f32x4 a0 = {0.f, 0.f, 0.f, 0.f}, a1 = {0.f, 0.f, 0.f, 0.f};
#pragma unroll
      for (int kk = 0; kk < 4; ++kk) {
        short8 k0 = *(const short8*)&Ks[ks * 32 + l16][kk * 32 + quad * 8];
        short8 k1 = *(const short8*)&Ks[ks * 32 + 16 + l16][kk * 32 + quad * 8];
        a0 = __builtin_amdgcn_mfma_f32_16x16x32_bf16(qh[kk], k0, a0, 0, 0, 0);
        a0 = __builtin_amdgcn_mfma_f32_16x16x32_bf16(ql[kk], k0, a0, 0, 0, 0);
        a1 = __builtin_amdgcn_mfma_f32_16x16x32_bf16(qh[kk], k1, a1, 0, 0, 0);
        a1 = __builtin_amdgcn_mfma_f32_16x16x32_bf16(ql[kk], k1, a1, 0, 0, 0);
      }
#pragma unroll
      for (int r = 0; r < 4; ++r) {
        float e0 = __expf(a0[r]);
        float e1 = __expf(a1[r]);
        lsum[r] += e0 + e1;
        Ps[wave][quad * 4 + r][l16]      = bfr(e0);
        Ps[wave][quad * 4 + r][l16 + 16] = bfr(e1);
      }
      // wave-private LDS round-trip (C-layout -> A-layout); no barrier needed
      short8 pa = *(const short8*)&Ps[wave][l16][quad * 8];
#pragma unroll
      for (int dt = 0; dt < 8; ++dt) {
        short8 vf = *(const short8*)&Vs[dt * 16 + l16][ks * 32 + quad * 8];
        oacc[dt] = __builtin_amdgcn_mfma_f32_16x16x32_bf16(pa, vf, oacc[dt], 0, 0, 0);
      }
    }
  }

  // ---- reduce row sums across the 16 lanes of each quad ----
#pragma unroll
  for (int r = 0; r < 4; ++r) {
    float s = lsum[r];
    s += __shfl_xor(s, 1, 16);
    s += __shfl_xor(s, 2, 16);
    s += __shfl_xor(s, 4, 16);
    s += __shfl_xor(s, 8, 16);
    float li = 1.0f / s;
    if (l16 == 0)
      linv_ws[(size_t)b * NL + i0 + wave * 16 + quad * 4 + r] = li;
    float* crow = ctx + ((size_t)b * NL + i0 + wave * 16 + quad * 4 + r) * ND;
#pragma unroll
    for (int dt = 0; dt < 8; ++dt)
      crow[dt * 16 + l16] = oacc[dt][r] * li;
  }
}

// ---------------- kernel B: attention = exp(QK^T)*linv ----------------
// grid (16 j-tiles, 32 i-tiles, 16 b) = 8192 blocks; block 256 = 4 waves x 16 rows.
// Stage K tile (128 j x 128 d) once, ONE barrier, then LDS frag reads + MFMA + stores.
__global__ __launch_bounds__(256, 4)
void attn_probs(const float* __restrict__ q, const unsigned short* __restrict__ Kb,
                const float* __restrict__ linv_ws, float* __restrict__ attn) {
  __shared__ unsigned short Ks[128][136];

  const int b    = blockIdx.z;
  const int i0   = blockIdx.y * 64;
  const int j0   = blockIdx.x * 128;
  const int tid  = threadIdx.x;
  const int wave = tid >> 6;
  const int lane = tid & 63;
  const int quad = lane >> 4;
  const int l16  = lane & 15;
  const int row0 = i0 + wave * 16;

  const float* qrow = q + ((size_t)b * NL + row0 + l16) * ND;
  short8 qh[4], ql[4];
  load_q_frags(qrow, quad, qh, ql);

  float li[4];
#pragma unroll
  for (int r = 0; r < 4; ++r)
    li[r] = linv_ws[(size_t)b * NL + row0 + quad * 4 + r];

  const unsigned short* kbb = Kb + (size_t)b * NL * ND;
#pragma unroll
  for (int r = 0; r < 8; ++r) {
    int c = tid + r * 256;
    int row = c >> 4, c8 = c & 15;
    *(short8*)&Ks[row][c8 * 8] =
        *(const short8*)(kbb + (size_t)(j0 + row) * ND + c8 * 8);
  }
  __syncthreads();

#pragma unroll
  for (int jg = 0; jg < 8; ++jg) {
    f32x4 a = {0.f, 0.f, 0.f, 0.f};
#pragma unroll
    for (int kk = 0; kk < 4; ++kk) {
      short8 kf = *(const short8*)&Ks[jg * 16 + l16][kk * 32 + quad * 8];
      a = __builtin_amdgcn_mfma_f32_16x16x32_bf16(qh[kk], kf, a, 0, 0, 0);
      a = __builtin_amdgcn_mfma_f32_16x16x32_bf16(ql[kk], kf, a, 0, 0, 0);
    }
    float* arow = attn + ((size_t)b * NL + row0 + quad * 4) * NL + j0 + jg * 16;
#pragma unroll
    for (int r = 0; r < 4; ++r)
      arow[(size_t)r * NL + l16] = __expf(a[r]) * li[r];
  }
}

// ---------------- fallback: round-2 monolithic (used only if ws too small) ----------------
__global__ __launch_bounds__(256, 2)
void attn_fused(const float* __restrict__ q, const float* __restrict__ kg,
                const float* __restrict__ vg, float* __restrict__ out) {
  float* ctx  = out;
  float* attn = out + (size_t)NB * NL * ND;
  const int b    = blockIdx.y;
  const int i0   = blockIdx.x * 64;
  const int tid  = threadIdx.x;
  const int wave = tid >> 6;
  const int lane = tid & 63;
  const int quad = lane >> 4;
  const int l16  = lane & 15;

  __shared__ short Ksf[32][136];
  __shared__ short Vtf[128][40];
  __shared__ short Ps2[4][16][40];

  const float* qrow = q + ((size_t)b * NL + i0 + wave * 16 + l16) * ND;
  short8 qh[4], ql[4];
  load_q_frags(qrow, quad, qh, ql);

  f32x4 oacc[8];
#pragma unroll
  for (int i = 0; i < 8; ++i) oacc[i] = (f32x4){0.f, 0.f, 0.f, 0.f};
  float lsum[4] = {0.f, 0.f, 0.f, 0.f};

  const float* kb = kg + (size_t)b * NL * ND;
  const float* vb = vg + (size_t)b * NL * ND;

  for (int j0 = 0; j0 < NL; j0 += 32) {
    __syncthreads();
#pragma unroll
    for (int rr = 0; rr < 4; ++rr) {
      int idx = tid + rr * 256;
      int row = idx >> 5;
      int c4  = idx & 31;
      float4 kv = *(const float4*)(kb + (size_t)(j0 + row) * ND + c4 * 4);
      ushort4 ks;
      ks.x = bfr(kv.x); ks.y = bfr(kv.y); ks.z = bfr(kv.z); ks.w = bfr(kv.w);
      *(ushort4*)&Ksf[row][c4 * 4] = ks;
      float4 vv = *(const float4*)(vb + (size_t)(j0 + row) * ND + c4 * 4);
      Vtf[c4 * 4 + 0][row] = (short)bfr(vv.x);
      Vtf[c4 * 4 + 1][row] = (short)bfr(vv.y);
      Vtf[c4 * 4 + 2][row] = (short)bfr(vv.z);
      Vtf[c4 * 4 + 3][row] = (short)bfr(vv.w);
    }
    __syncthreads();

    f32x4 a0 = {0.f, 0.f, 0.f, 0.f}, a1 = {0.f, 0.f, 0.f, 0.f};
#pragma unroll
    for (int kk = 0; kk < 4; ++kk) {
      short8 k0 = *(const short8*)&Ksf[l16][kk * 32 + quad * 8];
      short8 k1 = *(const short8*)&Ksf[l16 + 16][kk * 32 + quad * 8];
      a0 = __builtin_amdgcn_mfma_f32_16x16x32_bf16(qh[kk], k0, a0, 0, 0, 0);
      a0 = __builtin_amdgcn_mfma_f32_16x16x32_bf16(ql[kk], k0, a0, 0, 0, 0);
      a1 = __builtin_amdgcn_mfma_f32_16x16x32_bf16(qh[kk], k1, a1, 0, 0, 0);
      a1 = __builtin_amdgcn_mfma_f32_16x16x32_bf16(ql[kk], k1, a1, 0, 0, 0);
    }
#pragma unroll
    for (int r = 0; r < 4; ++r) {
      float e0 = __expf(a0[r]);
      float e1 = __expf(a1[r]);
      lsum[r] += e0 + e1;
      Ps2[wave][quad * 4 + r][l16]      = (short)bfr(e0);
      Ps2[wave][quad * 4 + r][l16 + 16] = (short)bfr(e1);
    }
    __syncthreads();
    short8 pa = *(const short8*)&Ps2[wave][l16][quad * 8];
#pragma unroll
    for (int dt = 0; dt < 8; ++dt) {
      short8 vf = *(const short8*)&Vtf[dt * 16 + l16][quad * 8];
      oacc[dt] = __builtin_amdgcn_mfma_f32_16x16x32_bf16(pa, vf, oacc[dt], 0, 0, 0);
    }
  }

  float linv[4];
#pragma unroll
  for (int r = 0; r < 4; ++r) {
    float s = lsum[r];
    s += __shfl_xor(s, 1, 16);
    s += __shfl_xor(s, 2, 16);
    s += __shfl_xor(s, 4, 16);
    s += __shfl_xor(s, 8, 16);
    linv[r] = 1.0f / s;
  }
#pragma unroll
  for (int r = 0; r < 4; ++r) {
    float* crow = ctx + ((size_t)b * NL + i0 + wave * 16 + quad * 4 + r) * ND;
#pragma unroll
    for (int dt = 0; dt < 8; ++dt)
      crow[dt * 16 + l16] = oacc[dt][r] * linv[r];
  }

  for (int j0 = 0; j0 < NL; j0 += 32) {
    __syncthreads();
#pragma unroll
    for (int rr = 0; rr < 4; ++rr) {
      int idx = tid + rr * 256;
      int row = idx >> 5;
      int c4  = idx & 31;
      float4 kv = *(const float4*)(kb + (size_t)(j0 + row) * ND + c4 * 4);
      ushort4 ks;
      ks.x = bfr(kv.x); ks.y = bfr(kv.y); ks.z = bfr(kv.z); ks.w = bfr(kv.w);
      *(ushort4*)&Ksf[row][c4 * 4] = ks;
    }
    __syncthreads();
    f32x4 a0 = {0.f, 0.f, 0.f, 0.f}, a1 = {0.f, 0.f, 0.f, 0.f};
#pragma unroll
    for (int kk = 0; kk < 4; ++kk) {
      short8 k0 = *(const short8*)&Ksf[l16][kk * 32 + quad * 8];
      short8 k1 = *(const short8*)&Ksf[l16 + 16][kk * 32 + quad * 8];
      a0 = __builtin_amdgcn_mfma_f32_16x16x32_bf16(qh[kk], k0, a0, 0, 0, 0);
      a0 = __builtin_amdgcn_mfma_f32_16x16x32_bf16(ql[kk], k0, a0, 0, 0, 0);
      a1 = __builtin_amdgcn_mfma_f32_16x16x32_bf16(qh[kk], k1, a1, 0, 0, 0);
      a1 = __builtin_amdgcn_mfma_f32_16x16x32_bf16(ql[kk], k1, a1, 0, 0, 0);
    }
    float* arow = attn + ((size_t)b * NL + i0 + wave * 16 + quad * 4) * NL + j0;
#pragma unroll
    for (int r = 0; r < 4; ++r) {
      arow[(size_t)r * NL + l16]      = __expf(a0[r]) * linv[r];
      arow[(size_t)r * NL + l16 + 16] = __expf(a1[r]) * linv[r];
    }
  }
}

extern "C" void kernel_launch(void* const* d_in, const int* in_sizes, int n_in,
                              void* d_out, int out_size, void* d_ws, size_t ws_size,
                              hipStream_t stream) {
  const float* q = (const float*)d_in[0];
  const float* k = (const float*)d_in[1];
  const float* v = (const float*)d_in[2];
  float* out = (float*)d_out;

  if (ws_size >= (size_t)WS_NEED) {
    unsigned short* Kb = (unsigned short*)((char*)d_ws + WS_KB);
    unsigned short* Vt = (unsigned short*)((char*)d_ws + WS_VT);
    float* linv        = (float*)((char*)d_ws + WS_LINV);
    float* ctx  = out;
    float* attn = out + (size_t)NB * NL * ND;

    prep_k<<<dim3(4096), dim3(256), 0, stream>>>(k, Kb);
    prep_vt<<<dim3(64, 16), dim3(256), 0, stream>>>(v, Vt);
    attn_ctx<<<dim3(32, 16), dim3(256), 0, stream>>>(q, Kb, Vt, ctx, linv);
    attn_probs<<<dim3(16, 32, 16), dim3(256), 0, stream>>>(q, Kb, linv, attn);
  } else {
    dim3 grid(NL / 64, NB);
    attn_fused<<<grid, dim3(256), 0, stream>>>(q, k, v, out);
  }
}